// Round 4
// baseline (542.073 us; speedup 1.0000x reference)
//
#include <hip/hip_runtime.h>
#include <hip/hip_bf16.h>
#include <stdint.h>

typedef __attribute__((ext_vector_type(8))) short bf16x8;
typedef __attribute__((ext_vector_type(4))) float f32x4;
typedef __attribute__((ext_vector_type(4))) unsigned short us4;
typedef __attribute__((ext_vector_type(8))) unsigned short us8;

__device__ __forceinline__ unsigned short f2bf(float f) {
  union { float f; unsigned int u; } v; v.f = f;
  unsigned int u = v.u;
  return (unsigned short)((u + 0x7FFFu + ((u >> 16) & 1u)) >> 16);
}
__device__ __forceinline__ float bf2f(unsigned short h) {
  union { unsigned int u; float f; } v; v.u = ((unsigned int)h) << 16;
  return v.f;
}

// ---------------------------------------------------------------------------
// NT GEMM: C[M,N] = A[M,K] * Bt[N,K]^T  (A row-major lda=K, Bt row-major ldb=K)
// EPI 0: store bf16 C row-major (ldc=N)
// EPI 1: attn epilogue: s=acc/32; s=(s<0.9)?0:s; e=exp(s); store **f32** e;
//        write per-(row, col-block) partial row sums of e to `partials`
// EPI 2: store bf16 C TRANSPOSED: Ct[b][col][row], batch folded in M
//        (2048 rows/batch, per-batch stride sC, ldc_t = 2048)
// AF32:  A is fp32 (converted to bf16 during staging)
// ---------------------------------------------------------------------------
template <int EPI, bool AF32>
__global__ __launch_bounds__(256, 2)
void gemm_nt(const void* __restrict__ Ap, const unsigned short* __restrict__ Btp,
             void* __restrict__ Cp, float* __restrict__ partials,
             int M, int N, int K, int nbm, int nbn,
             long long sA, long long sB, long long sC)
{
  const int tid = threadIdx.x;
  const int lane = tid & 63;
  const int wid = tid >> 6;
  const int wr = wid >> 1, wc = wid & 1;
  const int bb = blockIdx.y;
  const int bm = blockIdx.x % nbm, bn = blockIdx.x / nbm;
  const int row0 = bm * 128, col0 = bn * 128;

  __shared__ unsigned short lsA[128 * 64];   // [row][64] bf16, 16B-slot XOR swizzled
  __shared__ unsigned short lsB[128 * 64];
  __shared__ float srow2[128][2];

  const float* Af = (const float*)Ap + (AF32 ? (long long)bb * sA : 0ll);
  const unsigned short* Ab = (const unsigned short*)Ap + (AF32 ? 0ll : (long long)bb * sA);
  const unsigned short* Bb = Btp + (long long)bb * sB;

  f32x4 acc[4][4];
#pragma unroll
  for (int i = 0; i < 4; ++i)
#pragma unroll
    for (int j = 0; j < 4; ++j) {
      f32x4 z = {0.f, 0.f, 0.f, 0.f};
      acc[i][j] = z;
    }

  for (int k0 = 0; k0 < K; k0 += 64) {
    __syncthreads();
#pragma unroll
    for (int rep = 0; rep < 4; ++rep) {
      int idx = rep * 256 + tid;     // 0..1023 -> 128 rows x 8 16B-slots
      int r = idx >> 3, s = idx & 7;
      int ss = s ^ (r & 7);          // XOR swizzle (T2)
      us8 ta;
      if (AF32) {
        const float* pa = Af + (long long)(row0 + r) * K + (k0 + s * 8);
        f32x4 x0 = *(const f32x4*)pa;
        f32x4 x1 = *(const f32x4*)(pa + 4);
        ta[0] = f2bf(x0[0]); ta[1] = f2bf(x0[1]); ta[2] = f2bf(x0[2]); ta[3] = f2bf(x0[3]);
        ta[4] = f2bf(x1[0]); ta[5] = f2bf(x1[1]); ta[6] = f2bf(x1[2]); ta[7] = f2bf(x1[3]);
      } else {
        ta = *(const us8*)(Ab + (long long)(row0 + r) * K + (k0 + s * 8));
      }
      *(us8*)&lsA[r * 64 + ss * 8] = ta;
      us8 tb = *(const us8*)(Bb + (long long)(col0 + r) * K + (k0 + s * 8));
      *(us8*)&lsB[r * 64 + ss * 8] = tb;
    }
    __syncthreads();
#pragma unroll
    for (int kk = 0; kk < 2; ++kk) {
      int kslot = kk * 4 + (lane >> 4);
      bf16x8 af[4], bfg[4];
#pragma unroll
      for (int mf = 0; mf < 4; ++mf) {
        int rl = wr * 64 + mf * 16 + (lane & 15);
        af[mf] = *(const bf16x8*)&lsA[rl * 64 + ((kslot ^ (rl & 7)) * 8)];
      }
#pragma unroll
      for (int nf = 0; nf < 4; ++nf) {
        int cl = wc * 64 + nf * 16 + (lane & 15);
        bfg[nf] = *(const bf16x8*)&lsB[cl * 64 + ((kslot ^ (cl & 7)) * 8)];
      }
#pragma unroll
      for (int mf = 0; mf < 4; ++mf)
#pragma unroll
        for (int nf = 0; nf < 4; ++nf)
          acc[mf][nf] = __builtin_amdgcn_mfma_f32_16x16x32_bf16(af[mf], bfg[nf], acc[mf][nf], 0, 0, 0);
    }
  }

  if (EPI == 0) {
    unsigned short* C = (unsigned short*)Cp + (long long)bb * sC;
#pragma unroll
    for (int mf = 0; mf < 4; ++mf)
#pragma unroll
      for (int nf = 0; nf < 4; ++nf)
#pragma unroll
        for (int i = 0; i < 4; ++i) {
          int gr = row0 + wr * 64 + mf * 16 + (lane >> 4) * 4 + i;
          int gc = col0 + wc * 64 + nf * 16 + (lane & 15);
          C[(long long)gr * N + gc] = f2bf(acc[mf][nf][i]);
        }
  } else if (EPI == 2) {
    // transposed store: batch = gr>>11 (2048 rows/batch), Ct[b][gc][gr&2047]
    unsigned short* C = (unsigned short*)Cp;
#pragma unroll
    for (int mf = 0; mf < 4; ++mf)
#pragma unroll
      for (int nf = 0; nf < 4; ++nf) {
        int gr = row0 + wr * 64 + mf * 16 + (lane >> 4) * 4;  // rows gr..gr+3
        int gc = col0 + wc * 64 + nf * 16 + (lane & 15);
        int bb2 = gr >> 11, grb = gr & 2047;
        us4 o;
        o[0] = f2bf(acc[mf][nf][0]); o[1] = f2bf(acc[mf][nf][1]);
        o[2] = f2bf(acc[mf][nf][2]); o[3] = f2bf(acc[mf][nf][3]);
        *(us4*)&C[(long long)bb2 * sC + (long long)gc * 2048 + grb] = o;
      }
  } else {
    float* C = (float*)Cp + (long long)bb * sC;
    float rs[4][4];
#pragma unroll
    for (int mf = 0; mf < 4; ++mf)
#pragma unroll
      for (int i = 0; i < 4; ++i) rs[mf][i] = 0.f;
#pragma unroll
    for (int mf = 0; mf < 4; ++mf)
#pragma unroll
      for (int nf = 0; nf < 4; ++nf)
#pragma unroll
        for (int i = 0; i < 4; ++i) {
          int gr = row0 + wr * 64 + mf * 16 + (lane >> 4) * 4 + i;
          int gc = col0 + wc * 64 + nf * 16 + (lane & 15);
          float s = acc[mf][nf][i] * 0.03125f;   // 1/sqrt(1024)
          s = (s < 0.9f) ? 0.f : s;              // hard threshold BEFORE softmax
          float e = __expf(s);                   // bounded by exp(~6): no max-sub
          C[(long long)gr * N + gc] = e;         // f32 store (output dtype!)
          rs[mf][i] += e;
        }
#pragma unroll
    for (int mf = 0; mf < 4; ++mf)
#pragma unroll
      for (int i = 0; i < 4; ++i) {
        float vv = rs[mf][i];
        vv += __shfl_xor(vv, 1); vv += __shfl_xor(vv, 2);
        vv += __shfl_xor(vv, 4); vv += __shfl_xor(vv, 8);
        if ((lane & 15) == 0)
          srow2[wr * 64 + mf * 16 + (lane >> 4) * 4 + i][wc] = vv;
      }
    __syncthreads();
    if (tid < 128) {
      int gr = row0 + tid;
      partials[((long long)bb * M + gr) * nbn + bn] = srow2[tid][0] + srow2[tid][1];
    }
  }
}

// ---------------------------------------------------------------------------
// W [1024][1024] fp32 -> WT [1024][1024] bf16 (transposed)
// ---------------------------------------------------------------------------
__global__ __launch_bounds__(256)
void wtrans(const float* __restrict__ W, unsigned short* __restrict__ WT) {
  __shared__ float t[32][33];
  const int bi = blockIdx.x, bj = blockIdx.y;
  const int c = threadIdx.x & 31;
  const int r0 = threadIdx.x >> 5;   // 0..7
#pragma unroll
  for (int j = 0; j < 4; ++j) {
    int r = r0 + j * 8;
    t[r][c] = W[(long long)(bi * 32 + r) * 1024 + bj * 32 + c];
  }
  __syncthreads();
#pragma unroll
  for (int j = 0; j < 4; ++j) {
    int r = r0 + j * 8;
    WT[(long long)(bj * 32 + r) * 1024 + bi * 32 + c] = f2bf(t[c][r]);
  }
}

// ---------------------------------------------------------------------------
// attn f32 rows: attn[row][:] *= 1/denom(row); denom = sum of 16 partials
// ---------------------------------------------------------------------------
__global__ __launch_bounds__(256)
void attn_norm(float* __restrict__ attn, const float* __restrict__ partials) {
  const long long row = blockIdx.x;
  const int tid = threadIdx.x;
  __shared__ float sden;
  if (tid < 64) {
    float v = (tid < 16) ? partials[row * 16 + tid] : 0.f;
    v += __shfl_xor(v, 1); v += __shfl_xor(v, 2);
    v += __shfl_xor(v, 4); v += __shfl_xor(v, 8);
    if (tid == 0) sden = v;
  }
  __syncthreads();
  const float inv = 1.0f / sden;
  f32x4 x0 = *(const f32x4*)(attn + row * 2048 + tid * 8);
  f32x4 x1 = *(const f32x4*)(attn + row * 2048 + tid * 8 + 4);
#pragma unroll
  for (int i = 0; i < 4; ++i) { x0[i] *= inv; x1[i] *= inv; }
  *(f32x4*)(attn + row * 2048 + tid * 8) = x0;
  *(f32x4*)(attn + row * 2048 + tid * 8 + 4) = x1;
}

// ---------------------------------------------------------------------------
// out(f32) = LayerNorm(fc(bf16) + q(f32)) * gamma + beta   (row = 1024)
// ---------------------------------------------------------------------------
__global__ __launch_bounds__(256)
void ln_kernel(const unsigned short* __restrict__ fc, const float* __restrict__ q,
               const float* __restrict__ gamma, const float* __restrict__ beta,
               float* __restrict__ out) {
  const long long row = blockIdx.x;
  const int tid = threadIdx.x;
  __shared__ float sb1[4], sb2[4];
  us4 hv = *(const us4*)(fc + row * 1024 + tid * 4);
  f32x4 qv = *(const f32x4*)(q + row * 1024 + tid * 4);
  float x0 = bf2f(hv[0]) + qv[0];
  float x1 = bf2f(hv[1]) + qv[1];
  float x2 = bf2f(hv[2]) + qv[2];
  float x3 = bf2f(hv[3]) + qv[3];
  float s = x0 + x1 + x2 + x3;
#pragma unroll
  for (int m = 1; m < 64; m <<= 1) s += __shfl_xor(s, m);
  if ((tid & 63) == 0) sb1[tid >> 6] = s;
  __syncthreads();
  const float mean = (sb1[0] + sb1[1] + sb1[2] + sb1[3]) * (1.0f / 1024.0f);
  float d0 = x0 - mean, d1 = x1 - mean, d2 = x2 - mean, d3 = x3 - mean;
  float vs = d0 * d0 + d1 * d1 + d2 * d2 + d3 * d3;
#pragma unroll
  for (int m = 1; m < 64; m <<= 1) vs += __shfl_xor(vs, m);
  if ((tid & 63) == 0) sb2[tid >> 6] = vs;
  __syncthreads();
  const float var = (sb2[0] + sb2[1] + sb2[2] + sb2[3]) * (1.0f / 1024.0f);
  const float r = rsqrtf(var + 1e-6f);
  f32x4 g = *(const f32x4*)(gamma + tid * 4);
  f32x4 bt = *(const f32x4*)(beta + tid * 4);
  f32x4 o;
  o[0] = d0 * r * g[0] + bt[0];
  o[1] = d1 * r * g[1] + bt[1];
  o[2] = d2 * r * g[2] + bt[2];
  o[3] = d3 * r * g[3] + bt[3];
  *(f32x4*)(out + row * 1024 + tid * 4) = o;
}

// ---------------------------------------------------------------------------
// OUTPUT IS F32 (reference returns float32):
//   d_out = [ out0 f32 [8,2048,1024] (64 MiB) | attn f32 [8,2048,2048] (128 MiB) ]
// d_out reuse as scratch (fully rewritten each call):
//   out0 region: vhT bf16 (32MB) @+0 and out_mid bf16 (32MB) @+32MB during the
//   pipeline; final LN store overwrites the whole region last.
//   attn region: exp-values f32, normalized in place (final output 1).
// ws (73 MB): WqT/WkT/WvT/WfcT @0/2/4/6MB; partials @8MB; qh @9MB; kh @41MB.
//   fc (bf16) reuses the qh slot after qh is dead.
// ---------------------------------------------------------------------------
extern "C" void kernel_launch(void* const* d_in, const int* in_sizes, int n_in,
                              void* d_out, int out_size, void* d_ws, size_t ws_size,
                              hipStream_t stream) {
  const float* q    = (const float*)d_in[0];
  const float* k    = (const float*)d_in[1];
  const float* v    = (const float*)d_in[2];
  const float* Wq   = (const float*)d_in[3];
  const float* Wk   = (const float*)d_in[4];
  const float* Wv   = (const float*)d_in[5];
  const float* Wfc  = (const float*)d_in[6];
  const float* gamma = (const float*)d_in[7];
  const float* beta  = (const float*)d_in[8];

  float* out0 = (float*)d_out;                                  // [8,2048,1024] f32
  float* attn = out0 + (long long)8 * 2048 * 1024;              // [8,2048,2048] f32

  char* ws = (char*)d_ws;
  unsigned short* WqT  = (unsigned short*)(ws);                  //  2MB
  unsigned short* WkT  = (unsigned short*)(ws + (2ll  << 20));   //  2MB
  unsigned short* WvT  = (unsigned short*)(ws + (4ll  << 20));   //  2MB
  unsigned short* WfcT = (unsigned short*)(ws + (6ll  << 20));   //  2MB
  float* partials      = (float*)(ws + (8ll  << 20));            //  1MB
  unsigned short* qh   = (unsigned short*)(ws + (9ll  << 20));   // 32MB bf16
  unsigned short* kh   = (unsigned short*)(ws + (41ll << 20));   // 32MB bf16
  unsigned short* fc   = qh;                                     // reuse after scores
  // bf16 scratch inside the (not-yet-final) out0 f32 region:
  unsigned short* vhT     = (unsigned short*)d_out;              // 32MB bf16
  unsigned short* out_mid = (unsigned short*)((char*)d_out + (32ll << 20)); // 32MB

  // 1. weight transpose + bf16 convert
  wtrans<<<dim3(32, 32), 256, 0, stream>>>(Wq, WqT);
  wtrans<<<dim3(32, 32), 256, 0, stream>>>(Wk, WkT);
  wtrans<<<dim3(32, 32), 256, 0, stream>>>(Wv, WvT);
  wtrans<<<dim3(32, 32), 256, 0, stream>>>(Wfc, WfcT);

  // 2. projections (batch folded into M=16384, weights shared)
  gemm_nt<0, true><<<dim3(128 * 8, 1), 256, 0, stream>>>(q, WqT, qh, nullptr,
      16384, 1024, 1024, 128, 8, 0, 0, 0);
  gemm_nt<0, true><<<dim3(128 * 8, 1), 256, 0, stream>>>(k, WkT, kh, nullptr,
      16384, 1024, 1024, 128, 8, 0, 0, 0);
  // v-projection writes its result directly TRANSPOSED: vhT[b][d][s]
  gemm_nt<2, true><<<dim3(128 * 8, 1), 256, 0, stream>>>(v, WvT, vhT, nullptr,
      16384, 1024, 1024, 128, 8, 0, 0, 1024ll * 2048);

  // 3. S = qh kh^T / 32; threshold; exp -> attn region (f32); partial row sums
  gemm_nt<1, false><<<dim3(16 * 16, 8), 256, 0, stream>>>(qh, kh, attn, partials,
      2048, 2048, 1024, 16, 16, 2048ll * 1024, 2048ll * 1024, 2048ll * 2048);

  // 4. attn = e / rowsum  (in place, f32; final output 1)
  attn_norm<<<dim3(16384), 256, 0, stream>>>(attn, partials);

  // 5. out_mid = attn(f32, AF32-staged) @ vh
  gemm_nt<0, true><<<dim3(16 * 8, 8), 256, 0, stream>>>(attn, vhT, out_mid, nullptr,
      2048, 1024, 2048, 16, 8, 2048ll * 2048, 1024ll * 2048, 2048ll * 1024);

  // 6. fc = out_mid @ Wfc   (into qh slot — qh is dead)
  gemm_nt<0, false><<<dim3(128 * 8, 1), 256, 0, stream>>>(out_mid, WfcT, fc, nullptr,
      16384, 1024, 1024, 128, 8, 0, 0, 0);

  // 7. out0 = LN(fc + q)  (f32 store; overwrites vhT/out_mid scratch — both dead)
  ln_kernel<<<dim3(16384), 256, 0, stream>>>(fc, q, gamma, beta, out0);
}

// Round 5
// 420.525 us; speedup vs baseline: 1.2890x; 1.2890x over previous
//
#include <hip/hip_runtime.h>
#include <hip/hip_bf16.h>
#include <stdint.h>

typedef __attribute__((ext_vector_type(8))) short bf16x8;
typedef __attribute__((ext_vector_type(4))) float f32x4;
typedef __attribute__((ext_vector_type(4))) unsigned short us4;
typedef __attribute__((ext_vector_type(8))) unsigned short us8;

__device__ __forceinline__ unsigned short f2bf(float f) {
  union { float f; unsigned int u; } v; v.f = f;
  unsigned int u = v.u;
  return (unsigned short)((u + 0x7FFFu + ((u >> 16) & 1u)) >> 16);
}
__device__ __forceinline__ float bf2f(unsigned short h) {
  union { unsigned int u; float f; } v; v.u = ((unsigned int)h) << 16;
  return v.f;
}

// async global->LDS, 16B per lane; dest = wave-uniform base + lane*16
__device__ __forceinline__ void gload16(const unsigned short* g, unsigned short* l) {
  __builtin_amdgcn_global_load_lds(
      (const __attribute__((address_space(1))) unsigned int*)g,
      (__attribute__((address_space(3))) unsigned int*)l, 16, 0, 0);
}

// ---------------------------------------------------------------------------
// NT GEMM: C[M,N] = A[M,K] * Bt[N,K]^T, A/B bf16 row-major (lda=ldb=K).
// Staging: global_load_lds width-16, pre-swizzled global source so linear LDS
// writes land XOR-swizzled (slot s = ss ^ (r&7), involution); ds_read applies
// the same swizzle -> conflict-free, zero staging VALU.
// EPI 0: bf16 C row-major             (projections, FC)
// EPI 1: s=acc/32; thr 0.9; e=exp(s); bf16 e + per-(row,bn) partial row sums
// EPI 2: bf16 C transposed Ct[b][col][row], batch = gr>>11   (v-projection)
// EPI 3: bf16 (acc * inv_dens[bb*2048+gr])                   (PV)
// ---------------------------------------------------------------------------
template <int EPI>
__global__ __launch_bounds__(256, 2)
void gemm_nt(const unsigned short* __restrict__ Ap, const unsigned short* __restrict__ Btp,
             void* __restrict__ Cp, float* __restrict__ extra,
             int M, int N, int K, int nbm,
             long long sA, long long sB, long long sC)
{
  const int tid = threadIdx.x;
  const int lane = tid & 63;
  const int wid = tid >> 6;
  const int wr = wid >> 1, wc = wid & 1;
  const int bb = blockIdx.y;
  const int bm = blockIdx.x % nbm, bn = blockIdx.x / nbm;
  const int row0 = bm * 128, col0 = bn * 128;

  __shared__ unsigned short lsA[128 * 64];   // [row][8 slots of 16B], swizzled
  __shared__ unsigned short lsB[128 * 64];
  __shared__ float srow2[128][2];

  const unsigned short* Ab = Ap + (long long)bb * sA;
  const unsigned short* Bb = Btp + (long long)bb * sB;

  // staging geometry: wave w covers tile rows [w*32, w*32+32); 4 issues of
  // 64 lanes x 16B each (8 rows/issue). Lane's global 16B-slot is constant:
  // s = (lane&7) ^ (lane>>3)  (since r&7 == lane>>3 for every issue).
  const int srow = wid * 32 + (lane >> 3);
  const int sslot = (lane & 7) ^ (lane >> 3);
  const unsigned short* Asrc = Ab + (long long)(row0 + srow) * K + sslot * 8;
  const unsigned short* Bsrc = Bb + (long long)(col0 + srow) * K + sslot * 8;
  unsigned short* ldsA0 = &lsA[wid * 2048];   // 256 slots * 8 elem
  unsigned short* ldsB0 = &lsB[wid * 2048];

  f32x4 acc[4][4];
#pragma unroll
  for (int i = 0; i < 4; ++i)
#pragma unroll
    for (int j = 0; j < 4; ++j) {
      f32x4 z = {0.f, 0.f, 0.f, 0.f};
      acc[i][j] = z;
    }

  for (int k0 = 0; k0 < K; k0 += 64) {
    __syncthreads();
#pragma unroll
    for (int it = 0; it < 4; ++it) {
      gload16(Asrc + (long long)it * 8 * K + k0, ldsA0 + it * 512);
      gload16(Bsrc + (long long)it * 8 * K + k0, ldsB0 + it * 512);
    }
    __syncthreads();   // compiler drains vmcnt(0) before barrier
#pragma unroll
    for (int kk = 0; kk < 2; ++kk) {
      int kslot = kk * 4 + (lane >> 4);
      bf16x8 af[4], bfg[4];
#pragma unroll
      for (int mf = 0; mf < 4; ++mf) {
        int rl = wr * 64 + mf * 16 + (lane & 15);
        af[mf] = *(const bf16x8*)&lsA[rl * 64 + ((kslot ^ (rl & 7)) * 8)];
      }
#pragma unroll
      for (int nf = 0; nf < 4; ++nf) {
        int cl = wc * 64 + nf * 16 + (lane & 15);
        bfg[nf] = *(const bf16x8*)&lsB[cl * 64 + ((kslot ^ (cl & 7)) * 8)];
      }
#pragma unroll
      for (int mf = 0; mf < 4; ++mf)
#pragma unroll
        for (int nf = 0; nf < 4; ++nf)
          acc[mf][nf] = __builtin_amdgcn_mfma_f32_16x16x32_bf16(af[mf], bfg[nf], acc[mf][nf], 0, 0, 0);
    }
  }

  if (EPI == 0) {
    unsigned short* C = (unsigned short*)Cp + (long long)bb * sC;
#pragma unroll
    for (int mf = 0; mf < 4; ++mf)
#pragma unroll
      for (int nf = 0; nf < 4; ++nf)
#pragma unroll
        for (int i = 0; i < 4; ++i) {
          int gr = row0 + wr * 64 + mf * 16 + (lane >> 4) * 4 + i;
          int gc = col0 + wc * 64 + nf * 16 + (lane & 15);
          C[(long long)gr * N + gc] = f2bf(acc[mf][nf][i]);
        }
  } else if (EPI == 2) {
    unsigned short* C = (unsigned short*)Cp;
#pragma unroll
    for (int mf = 0; mf < 4; ++mf)
#pragma unroll
      for (int nf = 0; nf < 4; ++nf) {
        int gr = row0 + wr * 64 + mf * 16 + (lane >> 4) * 4;  // rows gr..gr+3
        int gc = col0 + wc * 64 + nf * 16 + (lane & 15);
        int bb2 = gr >> 11, grb = gr & 2047;
        us4 o;
        o[0] = f2bf(acc[mf][nf][0]); o[1] = f2bf(acc[mf][nf][1]);
        o[2] = f2bf(acc[mf][nf][2]); o[3] = f2bf(acc[mf][nf][3]);
        *(us4*)&C[(long long)bb2 * sC + (long long)gc * 2048 + grb] = o;
      }
  } else if (EPI == 3) {
    unsigned short* C = (unsigned short*)Cp + (long long)bb * sC;
    const float* inv = extra + (long long)bb * 2048;
#pragma unroll
    for (int mf = 0; mf < 4; ++mf)
#pragma unroll
      for (int nf = 0; nf < 4; ++nf)
#pragma unroll
        for (int i = 0; i < 4; ++i) {
          int gr = row0 + wr * 64 + mf * 16 + (lane >> 4) * 4 + i;
          int gc = col0 + wc * 64 + nf * 16 + (lane & 15);
          C[(long long)gr * N + gc] = f2bf(acc[mf][nf][i] * inv[gr]);
        }
  } else {   // EPI 1: scores
    unsigned short* C = (unsigned short*)Cp + (long long)bb * sC;
    float rs[4][4];
#pragma unroll
    for (int mf = 0; mf < 4; ++mf)
#pragma unroll
      for (int i = 0; i < 4; ++i) rs[mf][i] = 0.f;
#pragma unroll
    for (int mf = 0; mf < 4; ++mf)
#pragma unroll
      for (int nf = 0; nf < 4; ++nf)
#pragma unroll
        for (int i = 0; i < 4; ++i) {
          int gr = row0 + wr * 64 + mf * 16 + (lane >> 4) * 4 + i;
          int gc = col0 + wc * 64 + nf * 16 + (lane & 15);
          float s = acc[mf][nf][i] * 0.03125f;   // 1/sqrt(1024)
          s = (s < 0.9f) ? 0.f : s;              // hard threshold BEFORE softmax
          float e = __expf(s);                   // bounded by ~e^6: no max-sub
          C[(long long)gr * N + gc] = f2bf(e);
          rs[mf][i] += e;
        }
#pragma unroll
    for (int mf = 0; mf < 4; ++mf)
#pragma unroll
      for (int i = 0; i < 4; ++i) {
        float vv = rs[mf][i];
        vv += __shfl_xor(vv, 1); vv += __shfl_xor(vv, 2);
        vv += __shfl_xor(vv, 4); vv += __shfl_xor(vv, 8);
        if ((lane & 15) == 0)
          srow2[wr * 64 + mf * 16 + (lane >> 4) * 4 + i][wc] = vv;
      }
    __syncthreads();
    if (tid < 128) {
      int gr = row0 + tid;
      extra[((long long)bb * M + gr) * 16 + bn] = srow2[tid][0] + srow2[tid][1];
    }
  }
}

// ---------------------------------------------------------------------------
// q,k,v fp32 [16777216] -> bf16, one pass (8 elem/thread)
// ---------------------------------------------------------------------------
__global__ __launch_bounds__(256)
void cvt3(const float* __restrict__ a, const float* __restrict__ b,
          const float* __restrict__ c, unsigned short* __restrict__ oa,
          unsigned short* __restrict__ ob, unsigned short* __restrict__ oc) {
  const long long i = ((long long)blockIdx.x * 256 + threadIdx.x) * 8;
#pragma unroll
  for (int p = 0; p < 3; ++p) {
    const float* src = (p == 0) ? a : (p == 1) ? b : c;
    unsigned short* dst = (p == 0) ? oa : (p == 1) ? ob : oc;
    f32x4 x0 = *(const f32x4*)(src + i);
    f32x4 x1 = *(const f32x4*)(src + i + 4);
    us8 o;
    o[0] = f2bf(x0[0]); o[1] = f2bf(x0[1]); o[2] = f2bf(x0[2]); o[3] = f2bf(x0[3]);
    o[4] = f2bf(x1[0]); o[5] = f2bf(x1[1]); o[6] = f2bf(x1[2]); o[7] = f2bf(x1[3]);
    *(us8*)(dst + i) = o;
  }
}

// ---------------------------------------------------------------------------
// W [1024][1024] fp32 -> WT [1024][1024] bf16 (transposed)
// ---------------------------------------------------------------------------
__global__ __launch_bounds__(256)
void wtrans(const float* __restrict__ W, unsigned short* __restrict__ WT) {
  __shared__ float t[32][33];
  const int bi = blockIdx.x, bj = blockIdx.y;
  const int c = threadIdx.x & 31;
  const int r0 = threadIdx.x >> 5;
#pragma unroll
  for (int j = 0; j < 4; ++j) {
    int r = r0 + j * 8;
    t[r][c] = W[(long long)(bi * 32 + r) * 1024 + bj * 32 + c];
  }
  __syncthreads();
#pragma unroll
  for (int j = 0; j < 4; ++j) {
    int r = r0 + j * 8;
    WT[(long long)(bj * 32 + r) * 1024 + bi * 32 + c] = f2bf(t[c][r]);
  }
}

// ---------------------------------------------------------------------------
// attn f32 output + inv_dens from bf16 exp-scores and partials
// ---------------------------------------------------------------------------
__global__ __launch_bounds__(256)
void attn_norm(const unsigned short* __restrict__ e, const float* __restrict__ partials,
               float* __restrict__ attn, float* __restrict__ inv_dens) {
  const long long row = blockIdx.x;
  const int tid = threadIdx.x;
  __shared__ float sden;
  if (tid < 64) {
    float v = (tid < 16) ? partials[row * 16 + tid] : 0.f;
    v += __shfl_xor(v, 1); v += __shfl_xor(v, 2);
    v += __shfl_xor(v, 4); v += __shfl_xor(v, 8);
    if (tid == 0) sden = v;
  }
  __syncthreads();
  const float inv = 1.0f / sden;
  if (tid == 0) inv_dens[row] = inv;
  us8 x = *(const us8*)(e + row * 2048 + tid * 8);
  f32x4 y0, y1;
#pragma unroll
  for (int i = 0; i < 4; ++i) { y0[i] = bf2f(x[i]) * inv; y1[i] = bf2f(x[i + 4]) * inv; }
  *(f32x4*)(attn + row * 2048 + tid * 8) = y0;
  *(f32x4*)(attn + row * 2048 + tid * 8 + 4) = y1;
}

// ---------------------------------------------------------------------------
// out(f32) = LayerNorm(fc(bf16) + q(f32)) * gamma + beta   (row = 1024)
// ---------------------------------------------------------------------------
__global__ __launch_bounds__(256)
void ln_kernel(const unsigned short* __restrict__ fc, const float* __restrict__ q,
               const float* __restrict__ gamma, const float* __restrict__ beta,
               float* __restrict__ out) {
  const long long row = blockIdx.x;
  const int tid = threadIdx.x;
  __shared__ float sb1[4], sb2[4];
  us4 hv = *(const us4*)(fc + row * 1024 + tid * 4);
  f32x4 qv = *(const f32x4*)(q + row * 1024 + tid * 4);
  float x0 = bf2f(hv[0]) + qv[0];
  float x1 = bf2f(hv[1]) + qv[1];
  float x2 = bf2f(hv[2]) + qv[2];
  float x3 = bf2f(hv[3]) + qv[3];
  float s = x0 + x1 + x2 + x3;
#pragma unroll
  for (int m = 1; m < 64; m <<= 1) s += __shfl_xor(s, m);
  if ((tid & 63) == 0) sb1[tid >> 6] = s;
  __syncthreads();
  const float mean = (sb1[0] + sb1[1] + sb1[2] + sb1[3]) * (1.0f / 1024.0f);
  float d0 = x0 - mean, d1 = x1 - mean, d2 = x2 - mean, d3 = x3 - mean;
  float vs = d0 * d0 + d1 * d1 + d2 * d2 + d3 * d3;
#pragma unroll
  for (int m = 1; m < 64; m <<= 1) vs += __shfl_xor(vs, m);
  if ((tid & 63) == 0) sb2[tid >> 6] = vs;
  __syncthreads();
  const float var = (sb2[0] + sb2[1] + sb2[2] + sb2[3]) * (1.0f / 1024.0f);
  const float r = rsqrtf(var + 1e-6f);
  f32x4 g = *(const f32x4*)(gamma + tid * 4);
  f32x4 bt = *(const f32x4*)(beta + tid * 4);
  f32x4 o;
  o[0] = d0 * r * g[0] + bt[0];
  o[1] = d1 * r * g[1] + bt[1];
  o[2] = d2 * r * g[2] + bt[2];
  o[3] = d3 * r * g[3] + bt[3];
  *(f32x4*)(out + row * 1024 + tid * 4) = o;
}

// ---------------------------------------------------------------------------
// d_out = [ out0 f32 64MB | attn f32 128MB ].  Scratch timeline:
//   attn region: qb@+0, kb@+32M, vb@+64M (cvt) -> qh@+96M (proj-q) ->
//                kh@+0 (proj-k, qb dead) -> attn f32 overwrites all (norm)
//   out0 region: vhT@+0, out_mid@+32M; ln overwrites last.
// ws (~75MB): W*T @0/2/4/6M; partials@8M (2MB); inv_dens@10M; e bf16 @11M
//   (64MB, [8,2048,2048]); fc reuses e's first 32MB after PV consumed e.
// ---------------------------------------------------------------------------
extern "C" void kernel_launch(void* const* d_in, const int* in_sizes, int n_in,
                              void* d_out, int out_size, void* d_ws, size_t ws_size,
                              hipStream_t stream) {
  const float* q    = (const float*)d_in[0];
  const float* k    = (const float*)d_in[1];
  const float* v    = (const float*)d_in[2];
  const float* Wq   = (const float*)d_in[3];
  const float* Wk   = (const float*)d_in[4];
  const float* Wv   = (const float*)d_in[5];
  const float* Wfc  = (const float*)d_in[6];
  const float* gamma = (const float*)d_in[7];
  const float* beta  = (const float*)d_in[8];

  float* out0 = (float*)d_out;                                  // [8,2048,1024] f32
  float* attn = out0 + (long long)8 * 2048 * 1024;              // [8,2048,2048] f32

  char* ao = (char*)attn;   // attn region as scratch
  unsigned short* qb = (unsigned short*)(ao);                    // 32MB bf16
  unsigned short* kb = (unsigned short*)(ao + (32ll << 20));     // 32MB
  unsigned short* vb = (unsigned short*)(ao + (64ll << 20));     // 32MB
  unsigned short* qh = (unsigned short*)(ao + (96ll << 20));     // 32MB
  unsigned short* kh = (unsigned short*)(ao);                    // 32MB (qb dead)
  unsigned short* vhT     = (unsigned short*)d_out;              // 32MB (out0 region)
  unsigned short* out_mid = (unsigned short*)((char*)d_out + (32ll << 20)); // 32MB

  char* ws = (char*)d_ws;
  unsigned short* WqT  = (unsigned short*)(ws);
  unsigned short* WkT  = (unsigned short*)(ws + (2ll  << 20));
  unsigned short* WvT  = (unsigned short*)(ws + (4ll  << 20));
  unsigned short* WfcT = (unsigned short*)(ws + (6ll  << 20));
  float* partials      = (float*)(ws + (8ll  << 20));            // 2MB [8*2048][16]
  float* inv_dens      = (float*)(ws + (10ll << 20));            // 64KB [16384]
  unsigned short* e    = (unsigned short*)(ws + (11ll << 20));   // 64MB [8,2048,2048]
  unsigned short* fc   = e;                                      // reuse after PV

  // 1. input conversions
  cvt3<<<dim3(8192), 256, 0, stream>>>(q, k, v, qb, kb, vb);
  wtrans<<<dim3(32, 32), 256, 0, stream>>>(Wq, WqT);
  wtrans<<<dim3(32, 32), 256, 0, stream>>>(Wk, WkT);
  wtrans<<<dim3(32, 32), 256, 0, stream>>>(Wv, WvT);
  wtrans<<<dim3(32, 32), 256, 0, stream>>>(Wfc, WfcT);

  // 2. projections (batch folded into M=16384)
  gemm_nt<0><<<dim3(1024, 1), 256, 0, stream>>>(qb, WqT, qh, nullptr,
      16384, 1024, 1024, 128, 0, 0, 0);
  gemm_nt<0><<<dim3(1024, 1), 256, 0, stream>>>(kb, WkT, kh, nullptr,
      16384, 1024, 1024, 128, 0, 0, 0);
  gemm_nt<2><<<dim3(1024, 1), 256, 0, stream>>>(vb, WvT, vhT, nullptr,
      16384, 1024, 1024, 128, 0, 0, 1024ll * 2048);   // vhT[b][d][s]

  // 3. scores: e = exp(thresh(qh kh^T / 32)) bf16 + partial row sums
  gemm_nt<1><<<dim3(256, 8), 256, 0, stream>>>(qh, kh, e, partials,
      2048, 2048, 1024, 16, 2048ll * 1024, 2048ll * 1024, 2048ll * 2048);

  // 4. attn(f32) = e/den; inv_dens
  attn_norm<<<dim3(16384), 256, 0, stream>>>(e, partials, attn, inv_dens);

  // 5. PV: out_mid = (e @ vh) * inv_den[row]
  gemm_nt<3><<<dim3(128, 8), 256, 0, stream>>>(e, vhT, out_mid, inv_dens,
      2048, 1024, 2048, 16, 2048ll * 2048, 1024ll * 2048, 2048ll * 1024);

  // 6. FC: fc = out_mid @ Wfc  (out_mid contiguous as [16384,1024])
  gemm_nt<0><<<dim3(1024, 1), 256, 0, stream>>>(out_mid, WfcT, fc, nullptr,
      16384, 1024, 1024, 128, 0, 0, 0);

  // 7. out0 = LN(fc + q)
  ln_kernel<<<dim3(16384), 256, 0, stream>>>(fc, q, gamma, beta, out0);
}